// Round 11
// baseline (394.550 us; speedup 1.0000x reference)
//
#include <hip/hip_runtime.h>
#include <hip/hip_bf16.h>

// NPairLoss on MI355X (gfx950).
// loss = mean_i [ log( rowsum_i + e ) - pos_sim_i ] + 0.02*||examples||_F
// rowsum_i = sum_j exp(sim_ij), sim = (A/|A|)·(P/|P|)^T ; diag-replacement -> +e.
//
// R11: LDS-FREE fp8 GEMM. R7-R10 analysis: with MX-fp8's 2x MFMA rate the
// LDS staging+read path is the bound (256-384 KB LDS reads/block ~ 6200
// cyc/CU > 4400 cyc MFMA). So: operands go global->register directly (the
// 16 MB working set is L2/L3-resident), no LDS, no barriers, independent
// waves, TLP hides L2 latency (launch_bounds(256,4) caps VGPR at 128 ->
// 4 waves/SIMD). Fragment bytes per lane identical to the 4x-verified
// rdfrag mapping (row=base+ll, bytes s*128+lh*32, 2x16B); A and B share the
// k-mapping so any internal k-permutation cancels in A.B^T.

#define NR 8192
#define DD 512
#define E_CONST 2.71828182845904523536f

typedef __attribute__((ext_vector_type(4))) float f32x4_t;
typedef __attribute__((ext_vector_type(4))) int   i32x4_t;
typedef __attribute__((ext_vector_type(8))) int   i32x8_t;
typedef unsigned char uchar;
typedef unsigned int  uint;

// ---------------- prep: normalize rows -> fp8 e4m3, pos_sim, norm2, zero ----
__global__ __launch_bounds__(128) void prep_kernel(
    const float* __restrict__ ex,
    uchar* __restrict__ Ah, uchar* __restrict__ Ph,
    float* __restrict__ pos_sim, float* __restrict__ norm2,
    float* __restrict__ rowsum)
{
    const int i = blockIdx.x;
    const int t = threadIdx.x;            // 0..127, 4 floats each
    const float4 a = ((const float4*)(ex + (size_t)i * 1024))[t];
    const float4 p = ((const float4*)(ex + (size_t)i * 1024 + 512))[t];
    float sa  = a.x*a.x + a.y*a.y + a.z*a.z + a.w*a.w;
    float sp  = p.x*p.x + p.y*p.y + p.z*p.z + p.w*p.w;
    float sap = a.x*p.x + a.y*p.y + a.z*p.z + a.w*p.w;
    #pragma unroll
    for (int m = 1; m < 64; m <<= 1) {
        sa  += __shfl_xor(sa,  m, 64);
        sp  += __shfl_xor(sp,  m, 64);
        sap += __shfl_xor(sap, m, 64);
    }
    __shared__ float red[3][2];
    if ((t & 63) == 0) { red[0][t>>6] = sa; red[1][t>>6] = sp; red[2][t>>6] = sap; }
    __syncthreads();
    sa  = red[0][0] + red[0][1];
    sp  = red[1][0] + red[1][1];
    sap = red[2][0] + red[2][1];
    const float inva = rsqrtf(sa);
    const float invp = rsqrtf(sp);
    uint pa = 0, pp = 0;
    pa = __builtin_amdgcn_cvt_pk_fp8_f32(a.x * inva, a.y * inva, pa, false);
    pa = __builtin_amdgcn_cvt_pk_fp8_f32(a.z * inva, a.w * inva, pa, true);
    pp = __builtin_amdgcn_cvt_pk_fp8_f32(p.x * invp, p.y * invp, pp, false);
    pp = __builtin_amdgcn_cvt_pk_fp8_f32(p.z * invp, p.w * invp, pp, true);
    ((uint*)Ah)[i * 128 + t] = pa;
    ((uint*)Ph)[i * 128 + t] = pp;
    if (t == 0) {
        pos_sim[i] = sap * inva * invp;
        norm2[i]   = sa + sp;
        rowsum[i]  = 0.0f;
    }
}

// ---------------- GEMM 128^2 fp8, LDS-free, operands global->reg -------------
__global__ __launch_bounds__(256, 4) void gemm_kernel(
    const uchar* __restrict__ Ah, const uchar* __restrict__ Ph,
    float* __restrict__ rowsum)
{
    const int t  = threadIdx.x;           // 0..255
    const int w  = t >> 6;                // wave 0..3
    const int l  = t & 63;
    const int wr = w >> 1, wc = w & 1;    // 2M x 2N wave grid (64x64 per wave)
    const int ll = l & 15, lh = l >> 4;
    const int m0 = blockIdx.y * 128;
    const int n0 = blockIdx.x * 128;

    f32x4_t acc[4][4];
    #pragma unroll
    for (int i = 0; i < 4; i++)
        #pragma unroll
        for (int j = 0; j < 4; j++)
            acc[i][j] = (f32x4_t){0.f, 0.f, 0.f, 0.f};

    // per-lane fragment base: row = tile_base + ll, k-bytes lh*32 (+0/+16).
    // Same mapping for A and B (verified R7/R9/R10: absmax 0.0; common
    // k-permutation cancels in A.B^T).
    const uchar* Abase = Ah + (size_t)(m0 + wr * 64 + ll) * DD + lh * 32;
    const uchar* Bbase = Ph + (size_t)(n0 + wc * 64 + ll) * DD + lh * 32;

    #pragma unroll
    for (int s = 0; s < 4; ++s) {         // K slices of 128
        i32x8_t bf[4];
        #pragma unroll
        for (int ni = 0; ni < 4; ++ni) {
            const uchar* p = Bbase + ni * 16 * DD + s * 128;
            i32x4_t lo = *(const i32x4_t*)p;
            i32x4_t hi = *(const i32x4_t*)(p + 16);
            bf[ni] = __builtin_shufflevector(lo, hi, 0, 1, 2, 3, 4, 5, 6, 7);
        }
        #pragma unroll
        for (int mi = 0; mi < 4; ++mi) {
            const uchar* p = Abase + mi * 16 * DD + s * 128;
            i32x4_t lo = *(const i32x4_t*)p;
            i32x4_t hi = *(const i32x4_t*)(p + 16);
            i32x8_t af = __builtin_shufflevector(lo, hi, 0, 1, 2, 3, 4, 5, 6, 7);
            __builtin_amdgcn_s_setprio(1);
            #pragma unroll
            for (int ni = 0; ni < 4; ++ni)
                acc[mi][ni] =
                    __builtin_amdgcn_mfma_scale_f32_16x16x128_f8f6f4(
                        af, bf[ni], acc[mi][ni],
                        0, 0,                      // cbsz=fp8, blgp=fp8
                        0, 0x7F7F7F7F,             // scale A = 2^0
                        0, 0x7F7F7F7F);            // scale B = 2^0
            __builtin_amdgcn_s_setprio(0);
        }
    }

    // epilogue: per-row sum of exp over this block's 128 cols -> atomicAdd.
    // C/D (shape-determined): col = n0 + wc*64 + ni*16 + ll ;
    //                         row = m0 + wr*64 + mi*16 + lh*4 + r
    #pragma unroll
    for (int mi = 0; mi < 4; ++mi) {
        #pragma unroll
        for (int r = 0; r < 4; ++r) {
            float s = __expf(acc[mi][0][r]) + __expf(acc[mi][1][r]) +
                      __expf(acc[mi][2][r]) + __expf(acc[mi][3][r]);
            s += __shfl_xor(s, 1, 64);
            s += __shfl_xor(s, 2, 64);
            s += __shfl_xor(s, 4, 64);
            s += __shfl_xor(s, 8, 64);
            if (ll == 0)
                atomicAdd(&rowsum[m0 + wr * 64 + mi * 16 + lh * 4 + r], s);
        }
    }
}

// ---------------- final reduce (single block, fused) -------------------------
__global__ __launch_bounds__(1024) void final_kernel(
    const float* __restrict__ rowsum, const float* __restrict__ pos_sim,
    const float* __restrict__ norm2, float* __restrict__ out)
{
    const int t = threadIdx.x;
    float s1 = 0.f, s2 = 0.f;
    #pragma unroll
    for (int k = 0; k < NR / 1024; ++k) {
        const int i = k * 1024 + t;
        s1 += logf(rowsum[i] + E_CONST) - pos_sim[i];
        s2 += norm2[i];
    }
    #pragma unroll
    for (int m = 1; m < 64; m <<= 1) {
        s1 += __shfl_xor(s1, m, 64);
        s2 += __shfl_xor(s2, m, 64);
    }
    __shared__ float r1[16], r2[16];
    if ((t & 63) == 0) { r1[t >> 6] = s1; r2[t >> 6] = s2; }
    __syncthreads();
    if (t == 0) {
        float a = 0.f, b = 0.f;
        #pragma unroll
        for (int k = 0; k < 16; ++k) { a += r1[k]; b += r2[k]; }
        out[0] = a * (1.0f / NR) + 0.02f * sqrtf(b);
    }
}

extern "C" void kernel_launch(void* const* d_in, const int* in_sizes, int n_in,
                              void* d_out, int out_size, void* d_ws, size_t ws_size,
                              hipStream_t stream) {
    const float* ex = (const float*)d_in[0];
    float* out = (float*)d_out;
    char* ws = (char*)d_ws;
    uchar* Ah      = (uchar*)(ws);                          // 4 MiB
    uchar* Ph      = (uchar*)(ws + 4194304);                // 4 MiB
    float* possim  = (float*)(ws + 8388608);                // 32 KiB
    float* norm2   = (float*)(ws + 8388608 + 32768);        // 32 KiB
    float* rowsum  = (float*)(ws + 8388608 + 65536);        // 32 KiB

    prep_kernel<<<NR, 128, 0, stream>>>(ex, Ah, Ph, possim, norm2, rowsum);
    gemm_kernel<<<dim3(NR / 128, NR / 128), 256, 0, stream>>>(Ah, Ph, rowsum);
    final_kernel<<<1, 1024, 0, stream>>>(rowsum, possim, norm2, out);
}

// Round 12
// 211.364 us; speedup vs baseline: 1.8667x; 1.8667x over previous
//
#include <hip/hip_runtime.h>
#include <hip/hip_bf16.h>

// NPairLoss on MI355X (gfx950).
// loss = mean_i [ log( rowsum_i + e ) - pos_sim_i ] + 0.02*||examples||_F
// rowsum_i = sum_j exp(sim_ij), sim = (A/|A|)·(P/|P|)^T ; diag-replacement -> +e.
//
// R12: LDS-free fp8 GEMM (independent waves, no barriers), with R11's two
// failures fixed:
//  (1) launch_bounds(256,2): R11's (256,4) made the allocator shrink to 64
//      VGPR and spill acc (WRITE 622MB). Cap 256 removes the incentive.
//  (2) XCD supertile mapping (assumes round-robin XCD = bid&7, m157):
//      mb=(bid&7)*8+((bid>>3)&7), nb=bid>>6. Each XCD owns an exclusive
//      8-wide m-band; concurrent window = 8x8 block square per XCD ->
//      1 MB working set << 4 MB L2 (R11: scattered, FETCH 761 MB).
//  (3) epilogue: single-writer partial sums partial[128][8192] (written
//      exactly once, no zero-init needed) instead of 1M global atomics.
// Fragment mapping identical to the 5x-verified rdfrag bytes (row=base+ll,
// k-bytes s*128+lh*32, 2x16B); A,B share k-mapping -> permutation cancels.

#define NR 8192
#define DD 512
#define E_CONST 2.71828182845904523536f

typedef __attribute__((ext_vector_type(4))) float f32x4_t;
typedef __attribute__((ext_vector_type(4))) int   i32x4_t;
typedef __attribute__((ext_vector_type(8))) int   i32x8_t;
typedef unsigned char uchar;
typedef unsigned int  uint;

// ---------------- prep: normalize rows -> fp8 e4m3, pos_sim, norm2 ----------
__global__ __launch_bounds__(128) void prep_kernel(
    const float* __restrict__ ex,
    uchar* __restrict__ Ah, uchar* __restrict__ Ph,
    float* __restrict__ pos_sim, float* __restrict__ norm2,
    float* __restrict__ part)
{
    const int i = blockIdx.x;
    const int t = threadIdx.x;            // 0..127, 4 floats each
    const float4 a = ((const float4*)(ex + (size_t)i * 1024))[t];
    const float4 p = ((const float4*)(ex + (size_t)i * 1024 + 512))[t];
    float sa  = a.x*a.x + a.y*a.y + a.z*a.z + a.w*a.w;
    float sp  = p.x*p.x + p.y*p.y + p.z*p.z + p.w*p.w;
    float sap = a.x*p.x + a.y*p.y + a.z*p.z + a.w*p.w;
    #pragma unroll
    for (int m = 1; m < 64; m <<= 1) {
        sa  += __shfl_xor(sa,  m, 64);
        sp  += __shfl_xor(sp,  m, 64);
        sap += __shfl_xor(sap, m, 64);
    }
    __shared__ float red[3][2];
    if ((t & 63) == 0) { red[0][t>>6] = sa; red[1][t>>6] = sp; red[2][t>>6] = sap; }
    __syncthreads();
    sa  = red[0][0] + red[0][1];
    sp  = red[1][0] + red[1][1];
    sap = red[2][0] + red[2][1];
    const float inva = rsqrtf(sa);
    const float invp = rsqrtf(sp);
    uint pa = 0, pp = 0;
    pa = __builtin_amdgcn_cvt_pk_fp8_f32(a.x * inva, a.y * inva, pa, false);
    pa = __builtin_amdgcn_cvt_pk_fp8_f32(a.z * inva, a.w * inva, pa, true);
    pp = __builtin_amdgcn_cvt_pk_fp8_f32(p.x * invp, p.y * invp, pp, false);
    pp = __builtin_amdgcn_cvt_pk_fp8_f32(p.z * invp, p.w * invp, pp, true);
    ((uint*)Ah)[i * 128 + t] = pa;
    ((uint*)Ph)[i * 128 + t] = pp;
    if (t == 0) {
        pos_sim[i] = sap * inva * invp;
        norm2[i]   = sa + sp;
        if (i == 0) { part[0] = 0.0f; part[1] = 0.0f; }
    }
}

// ---------------- GEMM 128^2 fp8, LDS-free, XCD-supertiled -------------------
__global__ __launch_bounds__(256, 2) void gemm_kernel(
    const uchar* __restrict__ Ah, const uchar* __restrict__ Ph,
    float* __restrict__ partial)
{
    const int t  = threadIdx.x;           // 0..255
    const int w  = t >> 6;                // wave 0..3
    const int l  = t & 63;
    const int wr = w >> 1, wc = w & 1;    // 2M x 2N wave grid (64x64 per wave)
    const int ll = l & 15, lh = l >> 4;

    // XCD supertile (assumes XCD = bid&7 round-robin):
    // mb in XCD-exclusive band, nb advances every 64 bids.
    const int bid = blockIdx.x;
    const int mb  = ((bid & 7) << 3) | ((bid >> 3) & 7);   // 0..63
    const int nb  = bid >> 6;                              // 0..63
    const int m0 = mb * 128;
    const int n0 = nb * 128;

    f32x4_t acc[4][4];
    #pragma unroll
    for (int i = 0; i < 4; i++)
        #pragma unroll
        for (int j = 0; j < 4; j++)
            acc[i][j] = (f32x4_t){0.f, 0.f, 0.f, 0.f};

    // per-lane fragment base: row = tile_base + ll, k-bytes lh*32 (+0/+16).
    const uchar* Abase = Ah + (size_t)(m0 + wr * 64 + ll) * DD + lh * 32;
    const uchar* Bbase = Ph + (size_t)(n0 + wc * 64 + ll) * DD + lh * 32;

    #pragma unroll
    for (int s = 0; s < 4; ++s) {         // K slices of 128
        i32x8_t bf[4];
        #pragma unroll
        for (int ni = 0; ni < 4; ++ni) {
            const uchar* p = Bbase + ni * 16 * DD + s * 128;
            i32x4_t lo = *(const i32x4_t*)p;
            i32x4_t hi = *(const i32x4_t*)(p + 16);
            bf[ni] = __builtin_shufflevector(lo, hi, 0, 1, 2, 3, 4, 5, 6, 7);
        }
        #pragma unroll
        for (int mi = 0; mi < 4; ++mi) {
            const uchar* p = Abase + mi * 16 * DD + s * 128;
            i32x4_t lo = *(const i32x4_t*)p;
            i32x4_t hi = *(const i32x4_t*)(p + 16);
            i32x8_t af = __builtin_shufflevector(lo, hi, 0, 1, 2, 3, 4, 5, 6, 7);
            __builtin_amdgcn_s_setprio(1);
            #pragma unroll
            for (int ni = 0; ni < 4; ++ni)
                acc[mi][ni] =
                    __builtin_amdgcn_mfma_scale_f32_16x16x128_f8f6f4(
                        af, bf[ni], acc[mi][ni],
                        0, 0,                      // cbsz=fp8, blgp=fp8
                        0, 0x7F7F7F7F,             // scale A = 2^0
                        0, 0x7F7F7F7F);            // scale B = 2^0
            __builtin_amdgcn_s_setprio(0);
        }
    }

    // epilogue: per-row sum of exp over this wave's 64 cols; single-writer
    // store to partial[n_slice][row], n_slice = nb*2+wc (each cell written
    // exactly once -> no atomics, no zero-init).
    // C/D: col = n0 + wc*64 + ni*16 + ll ; row = m0 + wr*64 + mi*16 + lh*4 + r
    float* pslice = partial + (size_t)(nb * 2 + wc) * NR;
    #pragma unroll
    for (int mi = 0; mi < 4; ++mi) {
        #pragma unroll
        for (int r = 0; r < 4; ++r) {
            float s = __expf(acc[mi][0][r]) + __expf(acc[mi][1][r]) +
                      __expf(acc[mi][2][r]) + __expf(acc[mi][3][r]);
            s += __shfl_xor(s, 1, 64);
            s += __shfl_xor(s, 2, 64);
            s += __shfl_xor(s, 4, 64);
            s += __shfl_xor(s, 8, 64);
            if (ll == 0)
                pslice[m0 + wr * 64 + mi * 16 + lh * 4 + r] = s;
        }
    }
}

// ---------------- final: reduce 128 partials/row, then combine ---------------
__global__ __launch_bounds__(256) void final1_kernel(
    const float* __restrict__ partial, const float* __restrict__ pos_sim,
    const float* __restrict__ norm2, float* __restrict__ part)
{
    const int row = blockIdx.x * 256 + threadIdx.x;   // 32 blocks x 256
    float s = 0.f;
    #pragma unroll 8
    for (int k = 0; k < 128; ++k)
        s += partial[(size_t)k * NR + row];           // coalesced per k
    float s1 = logf(s + E_CONST) - pos_sim[row];
    float s2 = norm2[row];
    #pragma unroll
    for (int m = 1; m < 64; m <<= 1) {
        s1 += __shfl_xor(s1, m, 64);
        s2 += __shfl_xor(s2, m, 64);
    }
    if ((threadIdx.x & 63) == 0) {
        atomicAdd(&part[0], s1);
        atomicAdd(&part[1], s2);
    }
}

__global__ void final2_kernel(const float* __restrict__ part, float* __restrict__ out)
{
    out[0] = part[0] * (1.0f / NR) + 0.02f * sqrtf(part[1]);
}

extern "C" void kernel_launch(void* const* d_in, const int* in_sizes, int n_in,
                              void* d_out, int out_size, void* d_ws, size_t ws_size,
                              hipStream_t stream) {
    const float* ex = (const float*)d_in[0];
    float* out = (float*)d_out;
    char* ws = (char*)d_ws;
    uchar* Ah      = (uchar*)(ws);                          // 4 MiB
    uchar* Ph      = (uchar*)(ws + 4194304);                // 4 MiB
    float* possim  = (float*)(ws + 8388608);                // 32 KiB
    float* norm2   = (float*)(ws + 8388608 + 32768);        // 32 KiB
    float* part    = (float*)(ws + 8388608 + 65536);        // 8 B
    float* partial = (float*)(ws + 12582912);               // 4 MiB [128][8192]

    prep_kernel<<<NR, 128, 0, stream>>>(ex, Ah, Ph, possim, norm2, part);
    gemm_kernel<<<4096, 256, 0, stream>>>(Ah, Ph, partial);
    final1_kernel<<<NR / 256, 256, 0, stream>>>(partial, possim, norm2, part);
    final2_kernel<<<1, 1, 0, stream>>>(part, out);
}